// Round 1
// baseline (40.243 us; speedup 1.0000x reference)
//
#include <hip/hip_runtime.h>
#include <hip/hip_bf16.h>
#include <float.h>

#define INPUT_DIM 2304
#define SUB_DIM 64
#define ATOMS 512
#define NUM_EXPERTS 256
#define TOPK 4

// offset = 1/sqrt(2304) = 1/48 exactly (48^2 = 2304)
#define OFFSET (1.0f / 48.0f)

// ---------- block reduce (256 threads = 4 waves of 64) ----------
__device__ __forceinline__ float block_reduce_sum_256(float v, float* lds4) {
    // wave-level butterfly
    #pragma unroll
    for (int o = 32; o > 0; o >>= 1) v += __shfl_down(v, o);
    int lane = threadIdx.x & 63;
    int wave = threadIdx.x >> 6;
    if (lane == 0) lds4[wave] = v;
    __syncthreads();
    float r = 0.0f;
    if (threadIdx.x == 0) r = lds4[0] + lds4[1] + lds4[2] + lds4[3];
    return r; // valid only on thread 0
}

// ---------- K1: codes[e] = relu_off(enc_top[e] . x), slope 0 ----------
__global__ void codes_kernel(const float* __restrict__ enc_top,
                             const float* __restrict__ x,
                             float* __restrict__ codes) {
    __shared__ float lds4[4];
    int b = blockIdx.x;
    int t = threadIdx.x;
    const float* row = enc_top + (size_t)b * INPUT_DIM;
    float acc = 0.0f;
    #pragma unroll
    for (int i = 0; i < INPUT_DIM / 256; ++i) {
        int d = t + i * 256;
        acc += row[d] * x[d];
    }
    float s = block_reduce_sum_256(acc, lds4);
    if (t == 0) codes[b] = (s >= OFFSET) ? s : 0.0f;
}

// ---------- K2: top-4 of 256 codes (1 wave), ties -> lower index ----------
__global__ void topk_kernel(const float* __restrict__ codes,
                            int* __restrict__ idx,
                            float* __restrict__ val) {
    int t = threadIdx.x; // 64 threads
    float v[4];
    int   id[4];
    #pragma unroll
    for (int i = 0; i < 4; ++i) { id[i] = t + 64 * i; v[i] = codes[id[i]]; }
    for (int k = 0; k < TOPK; ++k) {
        // local best (value desc, index asc on ties)
        float bv = v[0]; int bi = id[0];
        #pragma unroll
        for (int i = 1; i < 4; ++i)
            if (v[i] > bv || (v[i] == bv && id[i] < bi)) { bv = v[i]; bi = id[i]; }
        // wave reduce
        float rv = bv; int ri = bi;
        #pragma unroll
        for (int o = 32; o > 0; o >>= 1) {
            float ov = __shfl_down(rv, o);
            int   oi = __shfl_down(ri, o);
            if (ov > rv || (ov == rv && oi < ri)) { rv = ov; ri = oi; }
        }
        rv = __shfl(rv, 0);
        ri = __shfl(ri, 0);
        if (t == 0) { idx[k] = ri; val[k] = rv; }
        // knock out the winner
        #pragma unroll
        for (int i = 0; i < 4; ++i)
            if (id[i] == ri) v[i] = -FLT_MAX;
    }
}

// ---------- K3: sub[e][s] = W_down[idx[e]][s] . x ----------
__global__ void subspace_kernel(const float* __restrict__ W_down,
                                const float* __restrict__ x,
                                const int* __restrict__ idx,
                                float* __restrict__ sub) {
    __shared__ float lds4[4];
    int e = blockIdx.x >> 6;   // 0..3
    int s = blockIdx.x & 63;   // 0..63
    int t = threadIdx.x;
    int E = idx[e];
    const float* row = W_down + ((size_t)E * SUB_DIM + s) * INPUT_DIM;
    float acc = 0.0f;
    #pragma unroll
    for (int i = 0; i < INPUT_DIM / 256; ++i) {
        int d = t + i * 256;
        acc += row[d] * x[d];
    }
    float r = block_reduce_sum_256(acc, lds4);
    if (t == 0) sub[e * SUB_DIM + s] = r;
}

// ---------- K4: per-expert: ec = relu_off(enc@sub, slope .01); dec = enc^T@ec ----------
__global__ void expert_kernel(const float* __restrict__ enc_w,
                              const float* __restrict__ sub,
                              const int* __restrict__ idx,
                              float* __restrict__ dec) {
    __shared__ float ssub[SUB_DIM];
    __shared__ float sec[ATOMS];
    __shared__ float red[256];
    int e = blockIdx.x;       // 0..3
    int t = threadIdx.x;      // 0..255
    int E = idx[e];
    if (t < SUB_DIM) ssub[t] = sub[e * SUB_DIM + t];
    __syncthreads();
    const float* W = enc_w + (size_t)E * ATOMS * SUB_DIM;
    #pragma unroll
    for (int r = 0; r < ATOMS / 256; ++r) {
        int a = t + r * 256;
        const float* row = W + a * SUB_DIM;
        float acc = 0.0f;
        #pragma unroll
        for (int s = 0; s < SUB_DIM; ++s) acc += row[s] * ssub[s];
        sec[a] = (acc >= OFFSET) ? acc : 0.01f * acc;
    }
    __syncthreads();
    // decoded[s] = sum_a W[a][s] * ec[a]; 4 groups of 128 atoms
    int s = t & 63;
    int g = t >> 6;
    float acc = 0.0f;
    for (int a = g * 128; a < (g + 1) * 128; ++a)
        acc += W[a * SUB_DIM + s] * sec[a];
    red[t] = acc;
    __syncthreads();
    if (t < SUB_DIM)
        dec[e * SUB_DIM + s] = red[s] + red[s + 64] + red[s + 128] + red[s + 192];
}

// ---------- K5: out[d] = sum_e val[e]*enc_top[idx[e]][d] + sum_{e,s} W_down[idx[e]][s][d]*dec[e][s] ----------
__global__ void recon_kernel(const float* __restrict__ W_down,
                             const float* __restrict__ enc_top,
                             const int* __restrict__ idx,
                             const float* __restrict__ val,
                             const float* __restrict__ dec,
                             float* __restrict__ out) {
    __shared__ float sdec[TOPK * SUB_DIM];
    __shared__ int   sidx[TOPK];
    __shared__ float sval[TOPK];
    int t = threadIdx.x;
    sdec[t] = dec[t];                     // 256 == TOPK*SUB_DIM
    if (t < TOPK) { sidx[t] = idx[t]; sval[t] = val[t]; }
    __syncthreads();
    int d = blockIdx.x * 256 + t;         // 9 blocks x 256 = 2304
    float acc = 0.0f;
    #pragma unroll
    for (int e = 0; e < TOPK; ++e) {
        int E = sidx[e];
        acc += sval[e] * enc_top[(size_t)E * INPUT_DIM + d];
        const float* W = W_down + (size_t)E * SUB_DIM * INPUT_DIM + d;
        #pragma unroll
        for (int s = 0; s < SUB_DIM; ++s)
            acc += W[(size_t)s * INPUT_DIM] * sdec[e * SUB_DIM + s];
    }
    out[d] = acc;
}

extern "C" void kernel_launch(void* const* d_in, const int* in_sizes, int n_in,
                              void* d_out, int out_size, void* d_ws, size_t ws_size,
                              hipStream_t stream) {
    const float* x          = (const float*)d_in[0];
    const float* enc_top    = (const float*)d_in[1];
    const float* W_down     = (const float*)d_in[2];
    const float* enc_w      = (const float*)d_in[3];
    float* out = (float*)d_out;

    // workspace layout (floats)
    float* ws    = (float*)d_ws;
    float* codes = ws;            // 256
    float* val   = ws + 256;      // 4
    float* sub   = ws + 260;      // 256
    float* dec   = ws + 516;      // 256
    int*   idx   = (int*)(ws + 772); // 4

    codes_kernel<<<NUM_EXPERTS, 256, 0, stream>>>(enc_top, x, codes);
    topk_kernel<<<1, 64, 0, stream>>>(codes, idx, val);
    subspace_kernel<<<TOPK * SUB_DIM, 256, 0, stream>>>(W_down, x, idx, sub);
    expert_kernel<<<TOPK, 256, 0, stream>>>(enc_w, sub, idx, dec);
    recon_kernel<<<INPUT_DIM / 256, 256, 0, stream>>>(W_down, enc_top, idx, val, dec, out);
}